// Round 3
// baseline (108.805 us; speedup 1.0000x reference)
//
#include <hip/hip_runtime.h>

// Reference: out[b,h,w,i] = in[b, h + i/8, w + i%8, 0]
//   in : (8, 512, 512, 1) f32   (8.4 MB, L2/L3-resident)
//   out: (8, 505, 505, 64) f32  (522 MB -> write-BW bound)
//
// One block per output row (b,h). Each thread writes one float4 of output
// (4 consecutive i), sourced by ONE unaligned 16B load (gfx950 supports
// 4B-aligned dwordx4): cuts VMEM instrs per 16B output from 5 to 2.

#define BATCH   8
#define W_IN    512
#define HW_OUT  505
#define ROW4    (HW_OUT * 16)   // 8080 float4 per (b,h) output row

typedef float f32x4 __attribute__((ext_vector_type(4)));

__global__ __launch_bounds__(256) void unfold_row_kernel(
    const float* __restrict__ in, float* __restrict__ out)
{
    int bh = blockIdx.x;               // 0..(8*505-1)
    int b  = bh / HW_OUT;
    int h  = bh - b * HW_OUT;

    const float* __restrict__ row_base = in + (b * W_IN + h) * W_IN;
    f32x4* __restrict__ out4 = reinterpret_cast<f32x4*>(out) + (size_t)bh * ROW4;

    for (int t = threadIdx.x; t < ROW4; t += 256) {
        int i4 = t & 15;               // which float4 within the 64-ch pixel
        int w  = t >> 4;               // output column
        // source: row h + (i4>>1), cols w + (i4&1)*4 .. +3  (row stride 512)
        int off = ((i4 >> 1) << 9) + w + ((i4 & 1) << 2);

        f32x4 v;
        __builtin_memcpy(&v, row_base + off, sizeof(f32x4));  // 16B load, 4B-aligned
        __builtin_nontemporal_store(v, out4 + t);
    }
}

extern "C" void kernel_launch(void* const* d_in, const int* in_sizes, int n_in,
                              void* d_out, int out_size, void* d_ws, size_t ws_size,
                              hipStream_t stream)
{
    const float* in  = (const float*)d_in[0];   // (8,512,512,1) f32
    float*       out = (float*)d_out;           // (8,505,505,64) f32

    const int grid = BATCH * HW_OUT;            // 4040 blocks, one per output row
    unfold_row_kernel<<<grid, 256, 0, stream>>>(in, out);
}